// Round 1
// baseline (897.103 us; speedup 1.0000x reference)
//
#include <hip/hip_runtime.h>
#include <cstdint>
#include <cstddef>

// WindowAttention: B=4096 windows, N=49 tokens, DIM=256, NH=8, HD=32.
// K0 weights->bf16T + padded bias table, K1 qkv GEMM (XCD-swizzled),
// K2 fused attention+projection v2: swapped QK^T (S^T in regs), in-register
// softmax (k-axis = 16 in-lane + cross-quad shfl), P kept in registers via
// cvt_pk_bf16 + ds_bpermute quad exchange (no LDS P roundtrip, no fences),
// mask staged once per block, bias from precomputed padded table,
// OutS aliased onto Vt -> 47 KB LDS -> 3 blocks/CU.

#define NTOK 49
#define SCALE 0.17677669529663687f

typedef unsigned short u16;
typedef __attribute__((ext_vector_type(8))) short short8;
typedef __attribute__((ext_vector_type(4))) float f32x4;

__device__ __forceinline__ u16 f2bf(float f) {
    unsigned int u = __float_as_uint(f);
    u = (u + 0x7FFFu + ((u >> 16) & 1u)) >> 16;   // RNE
    return (u16)u;
}

__device__ __forceinline__ unsigned cvt_pk_bf16(float lo, float hi) {
    unsigned r;
    asm("v_cvt_pk_bf16_f32 %0, %1, %2" : "=v"(r) : "v"(lo), "v"(hi));
    return r;
}

__device__ __forceinline__ void async_lds16(void* lds, const void* g) {
    __builtin_amdgcn_global_load_lds(
        (const __attribute__((address_space(1))) void*)g,
        (__attribute__((address_space(3))) void*)lds, 16, 0, 0);
}

// ---------------- K0: weights -> bf16T + padded bias table -----------------
// bias_p[h][q][k] (64x64 padded, -1e30 outside 49x49) replaces per-element
// rpb gather + index math in K2.
__global__ void prep_weights(const float* __restrict__ qkv_w,
                             const float* __restrict__ proj_w,
                             const float* __restrict__ rpb,
                             u16* __restrict__ qkv_wT,
                             u16* __restrict__ proj_wT,
                             float* __restrict__ bias_p) {
    int i = blockIdx.x * 256 + threadIdx.x;
    if (i < 768 * 256) {
        int oc = i >> 8, k = i & 255;
        qkv_wT[i] = f2bf(qkv_w[k * 768 + oc]);
    }
    int j = i - 768 * 256;
    if (j >= 0 && j < 256 * 256) {
        int oc = j >> 8, k = j & 255;
        proj_wT[j] = f2bf(proj_w[k * 256 + oc]);
    }
    int m = i - (768 * 256 + 256 * 256);
    if (m >= 0 && m < 8 * 64 * 64) {
        int h = m >> 12, q = (m >> 6) & 63, k = m & 63;
        float v = -1e30f;
        if (q < NTOK && k < NTOK) {
            int qr = q / 7, qc = q - qr * 7;
            int kr = k / 7, kc = k - kr * 7;
            v = rpb[((qr - kr + 6) * 13 + (qc - kc + 6)) * 8 + h];
        }
        bias_p[m] = v;
    }
}

// ---------------- K1: qkv = x @ qkv_w + b, q pre-scaled, bf16 out ----------
// M=200704 (1568 m-tiles of 128), N=768 (3 n-tiles of 256), K=256, BK=64.
// 512 thr = 8 waves (2m x 4n), 64x64 per wave. XCD-swizzled blockIdx (T1).
__global__ __launch_bounds__(512, 4) void qkv_gemm(
        const float* __restrict__ x, const u16* __restrict__ wT,
        const float* __restrict__ bias, u16* __restrict__ qkv) {
    __shared__ __align__(16) u16 As[128 * 64];   // unpadded (m97 pattern)
    __shared__ __align__(16) u16 Bs[256 * 64];   // unpadded: global_load_lds dest
    const int b0 = blockIdx.x;
    const int bid = (b0 & 7) * 588 + (b0 >> 3);  // 4704 = 8 * 588, bijective
    const int m0 = (bid % 1568) * 128, n0 = (bid / 1568) * 256;
    const int t = threadIdx.x;
    const int lane = t & 63, w = t >> 6;
    const int quad = lane >> 4, l16 = lane & 15;
    const int wm = w & 1, wn = w >> 1;
    const int ar = t >> 2, ac = (t & 3) * 16;          // A staging: 1 row-quarter
    const int br = t >> 3, bc = (t & 7) * 8;           // B staging row/col (elems)
    f32x4 acc[4][4] = {};
    for (int kk = 0; kk < 256; kk += 64) {
        #pragma unroll
        for (int c = 0; c < 4; ++c)                    // B: 256x64 bf16, async DMA
            async_lds16(&Bs[c * 4096 + t * 8],
                        wT + (size_t)(n0 + c * 64 + br) * 256 + kk + bc);
        {                                               // A: 128x64 f32 -> bf16
            const float* src = x + (size_t)(m0 + ar) * 256 + kk + ac;
            const f32x4 v0 = *(const f32x4*)(src);
            const f32x4 v1 = *(const f32x4*)(src + 4);
            const f32x4 v2 = *(const f32x4*)(src + 8);
            const f32x4 v3 = *(const f32x4*)(src + 12);
            ushort4 p0, p1, p2, p3;
            p0.x=f2bf(v0.x); p0.y=f2bf(v0.y); p0.z=f2bf(v0.z); p0.w=f2bf(v0.w);
            p1.x=f2bf(v1.x); p1.y=f2bf(v1.y); p1.z=f2bf(v1.z); p1.w=f2bf(v1.w);
            p2.x=f2bf(v2.x); p2.y=f2bf(v2.y); p2.z=f2bf(v2.z); p2.w=f2bf(v2.w);
            p3.x=f2bf(v3.x); p3.y=f2bf(v3.y); p3.z=f2bf(v3.z); p3.w=f2bf(v3.w);
            uint4 q0, q1;
            q0.x=*(unsigned*)&p0.x; q0.y=*(unsigned*)&p0.z;
            q0.z=*(unsigned*)&p1.x; q0.w=*(unsigned*)&p1.z;
            q1.x=*(unsigned*)&p2.x; q1.y=*(unsigned*)&p2.z;
            q1.z=*(unsigned*)&p3.x; q1.w=*(unsigned*)&p3.z;
            *(uint4*)&As[ar * 64 + ac] = q0;
            *(uint4*)&As[ar * 64 + ac + 8] = q1;
        }
        __syncthreads();
        #pragma unroll
        for (int ks = 0; ks < 2; ++ks) {
            short8 af[4], bfr[4];
            #pragma unroll
            for (int i = 0; i < 4; ++i)
                af[i] = *(const short8*)&As[(wm * 64 + i * 16 + l16) * 64 + ks * 32 + quad * 8];
            #pragma unroll
            for (int j = 0; j < 4; ++j)
                bfr[j] = *(const short8*)&Bs[(wn * 64 + j * 16 + l16) * 64 + ks * 32 + quad * 8];
            #pragma unroll
            for (int i = 0; i < 4; ++i)
                #pragma unroll
                for (int j = 0; j < 4; ++j)
                    acc[i][j] = __builtin_amdgcn_mfma_f32_16x16x32_bf16(
                        af[i], bfr[j], acc[i][j], 0, 0, 0);
        }
        __syncthreads();
    }
    #pragma unroll
    for (int j = 0; j < 4; ++j) {
        const int gc = n0 + wn * 64 + j * 16 + l16;
        const float bv = bias[gc];
        const float scl = (gc < 256) ? SCALE : 1.0f;
        #pragma unroll
        for (int i = 0; i < 4; ++i) {
            const int gr = m0 + wm * 64 + i * 16 + quad * 4;
            #pragma unroll
            for (int r = 0; r < 4; ++r)
                qkv[(size_t)(gr + r) * 768 + gc] = f2bf((acc[i][j][r] + bv) * scl);
        }
    }
}

// ---------------- K2: per-window attention + projection (v2) ---------------
// 1 block / window, 512 thr = 8 waves = 1 head each.
// LDS: SMEM 34816 B (Vt, later aliased by OutS) + maskL 13328 B = 47 KB
// -> 3 blocks/CU at <=84 VGPR (launch_bounds(512,6)).
__global__ __launch_bounds__(512, 6) void attn_proj(
        const u16* __restrict__ qkv, const float* __restrict__ mask,
        const float* __restrict__ bias_p, const u16* __restrict__ projT,
        const float* __restrict__ proj_b, float* __restrict__ out) {
    __shared__ __align__(16) u16 SMEM[8 * 32 * 68];   // V^T [h][d][tok]; OutS overlay later
    __shared__ __align__(16) float maskL[49 * 68];    // mask staged once per block
    const int b = blockIdx.x;
    const int t = threadIdx.x;
    const int lane = t & 63, h = t >> 6;              // wave == head
    const int quad = lane >> 4, l16 = lane & 15;
    const short8 zf = {0, 0, 0, 0, 0, 0, 0, 0};
    const f32x4 zero4 = {0.f, 0.f, 0.f, 0.f};
    const u16* qrow = qkv + (size_t)b * NTOK * 768;
    const float* mrow = mask + (size_t)b * (NTOK * NTOK);

    // ---- stage V^T: wave h stages head h; paired tokens -> b32 writes,
    //      bank-conflict-free; pad tokens (>=49) zero-filled inline ----
    {
        unsigned* vw = (unsigned*)&SMEM[h * 2176];
        const int tp = lane & 31;                     // token pair index
        const int dh = (lane >> 5) * 4;               // d sub-quad
        const int n0 = 2 * tp;
        #pragma unroll
        for (int it = 0; it < 4; ++it) {
            const int d0 = it * 8 + dh;
            ushort4 g0 = {0, 0, 0, 0}, g1 = {0, 0, 0, 0};
            if (n0 < NTOK)     g0 = *(const ushort4*)(qrow + n0 * 768 + 512 + h * 32 + d0);
            if (n0 + 1 < NTOK) g1 = *(const ushort4*)(qrow + (n0 + 1) * 768 + 512 + h * 32 + d0);
            vw[(d0 + 0) * 34 + tp] = (unsigned)g0.x | ((unsigned)g1.x << 16);
            vw[(d0 + 1) * 34 + tp] = (unsigned)g0.y | ((unsigned)g1.y << 16);
            vw[(d0 + 2) * 34 + tp] = (unsigned)g0.z | ((unsigned)g1.z << 16);
            vw[(d0 + 3) * 34 + tp] = (unsigned)g0.w | ((unsigned)g1.w << 16);
        }
    }
    // ---- stage mask [49][68] f32, once per block (waves share) ----
    for (int r = h; r < NTOK; r += 8) {
        maskL[r * 68 + lane] = (lane < NTOK) ? mrow[r * 49 + lane] : 0.f;
        if (lane < 4) maskL[r * 68 + 64 + lane] = 0.f;
    }
    __syncthreads();

    // ---- V frags (B operand for PV) into registers ----
    short8 bV[2][2];
    {
        const u16* vt = &SMEM[h * 2176];
        #pragma unroll
        for (int ct = 0; ct < 2; ++ct)
            #pragma unroll
            for (int ks = 0; ks < 2; ++ks)
                bV[ct][ks] = *(const short8*)&vt[(ct * 16 + l16) * 68 + ks * 32 + quad * 8];
    }
    // K frags (A operand of swapped QK^T): K token rows, contiguous d
    short8 aK[4];
    #pragma unroll
    for (int ki = 0; ki < 4; ++ki) {
        const int kt = ki * 16 + l16;
        aK[ki] = (kt < NTOK) ? *(const short8*)(qrow + kt * 768 + 256 + h * 32 + quad * 8) : zf;
    }
    __syncthreads();   // all bV register-resident before OutS overlays Vt

    u16* OutS = SMEM;  // overlay: [49][264] bf16, 25.9 KB <= 34.8 KB
    const float* bias_h = bias_p + (h << 12);
    const int saA = (((quad & 1) << 5) + l16) << 2;  // bpermute byte addr (quads 0/2)
    const int saB = saA + 64;                        // +16 lanes (quads 1/3)
    const bool hiK = (quad >> 1) != 0;

    // ---- per q-tile: QK^T (swapped) -> softmax in regs -> PV -> OutS ----
    #pragma unroll
    for (int qj = 0; qj < 4; ++qj) {
        const int qtok = qj * 16 + l16;              // this lane's q column
        const short8 bQ = (qtok < NTOK)
            ? *(const short8*)(qrow + qtok * 768 + h * 32 + quad * 8) : zf;
        f32x4 S[4];                                   // S^T[k=16ki+4*quad+r][qtok]
        #pragma unroll
        for (int ki = 0; ki < 4; ++ki)
            S[ki] = __builtin_amdgcn_mfma_f32_16x16x32_bf16(aK[ki], bQ, zero4, 0, 0, 0);
        // bias (padded table: -1e30 outside 49x49) + mask, float4 loads
        const int qc = (qtok < NTOK) ? qtok : 0;
        #pragma unroll
        for (int ki = 0; ki < 4; ++ki) {
            const f32x4 bb = *(const f32x4*)(bias_h + qtok * 64 + ki * 16 + quad * 4);
            const f32x4 mm = *(const f32x4*)(&maskL[qc * 68 + ki * 16 + quad * 4]);
            S[ki] += bb + mm;
        }
        // softmax over k: 16 in-lane + cross-quad (lanes l16 ^ 16 ^ 32)
        float mx = fmaxf(fmaxf(fmaxf(S[0][0], S[0][1]), fmaxf(S[0][2], S[0][3])),
                         fmaxf(fmaxf(S[1][0], S[1][1]), fmaxf(S[1][2], S[1][3])));
        mx = fmaxf(mx, fmaxf(fmaxf(fmaxf(S[2][0], S[2][1]), fmaxf(S[2][2], S[2][3])),
                             fmaxf(fmaxf(S[3][0], S[3][1]), fmaxf(S[3][2], S[3][3]))));
        mx = fmaxf(mx, __shfl_xor(mx, 16));
        mx = fmaxf(mx, __shfl_xor(mx, 32));
        float sum = 0.f;
        #pragma unroll
        for (int ki = 0; ki < 4; ++ki)
            #pragma unroll
            for (int r = 0; r < 4; ++r) {
                const float e = __expf(S[ki][r] - mx);
                S[ki][r] = e;
                sum += e;
            }
        sum += __shfl_xor(sum, 16);
        sum += __shfl_xor(sum, 32);
        const float rinv = 1.0f / sum;
        // pack P^T to bf16 pairs (r01, r23 per ki)
        unsigned pk2[4][2];
        #pragma unroll
        for (int ki = 0; ki < 4; ++ki) {
            pk2[ki][0] = cvt_pk_bf16(S[ki][0] * rinv, S[ki][1] * rinv);
            pk2[ki][1] = cvt_pk_bf16(S[ki][2] * rinv, S[ki][3] * rinv);
        }
        // quad exchange: A-frag word f of k-tile ks comes from lane
        // (2*(quad&1)+(f>>1))*16+l16, register pk2[2ks+(quad>>1)][f&1]
        f32x4 O0 = zero4, O1 = zero4;
        #pragma unroll
        for (int ks = 0; ks < 2; ++ks) {
            const int j0 = 2 * ks, j1 = 2 * ks + 1;
            const unsigned a0 = __builtin_amdgcn_ds_bpermute(saA, (int)pk2[j0][0]);
            const unsigned b0 = __builtin_amdgcn_ds_bpermute(saA, (int)pk2[j1][0]);
            const unsigned a1 = __builtin_amdgcn_ds_bpermute(saA, (int)pk2[j0][1]);
            const unsigned b1 = __builtin_amdgcn_ds_bpermute(saA, (int)pk2[j1][1]);
            const unsigned a2 = __builtin_amdgcn_ds_bpermute(saB, (int)pk2[j0][0]);
            const unsigned b2 = __builtin_amdgcn_ds_bpermute(saB, (int)pk2[j1][0]);
            const unsigned a3 = __builtin_amdgcn_ds_bpermute(saB, (int)pk2[j0][1]);
            const unsigned b3 = __builtin_amdgcn_ds_bpermute(saB, (int)pk2[j1][1]);
            union { unsigned u[4]; short8 s; } ap;
            ap.u[0] = hiK ? b0 : a0;
            ap.u[1] = hiK ? b1 : a1;
            ap.u[2] = hiK ? b2 : a2;
            ap.u[3] = hiK ? b3 : a3;
            O0 = __builtin_amdgcn_mfma_f32_16x16x32_bf16(ap.s, bV[0][ks], O0, 0, 0, 0);
            O1 = __builtin_amdgcn_mfma_f32_16x16x32_bf16(ap.s, bV[1][ks], O1, 0, 0, 0);
        }
        #pragma unroll
        for (int r = 0; r < 4; ++r) {
            const int row = qj * 16 + quad * 4 + r;
            if (row < NTOK) {
                OutS[row * 264 + h * 32 + l16]      = f2bf(O0[r]);
                OutS[row * 264 + h * 32 + 16 + l16] = f2bf(O1[r]);
            }
        }
    }
    __syncthreads();

    // ---- proj: [49x256] @ [256x256], wave h -> out cols h*32..h*32+31 ----
    f32x4 P2[4][2] = {};
    #pragma unroll
    for (int ks = 0; ks < 8; ++ks) {
        short8 bW[2];
        #pragma unroll
        for (int ct = 0; ct < 2; ++ct)
            bW[ct] = *(const short8*)(projT + (size_t)(h * 32 + ct * 16 + l16) * 256
                                      + ks * 32 + quad * 8);
        #pragma unroll
        for (int i = 0; i < 4; ++i) {
            const int row = i * 16 + l16;
            const short8 aO = (row < NTOK) ? *(const short8*)&OutS[row * 264 + ks * 32 + quad * 8] : zf;
            #pragma unroll
            for (int ct = 0; ct < 2; ++ct)
                P2[i][ct] = __builtin_amdgcn_mfma_f32_16x16x32_bf16(aO, bW[ct], P2[i][ct], 0, 0, 0);
        }
    }
    #pragma unroll
    for (int ct = 0; ct < 2; ++ct) {
        const int gc = h * 32 + ct * 16 + l16;
        const float pb = proj_b[gc];
        #pragma unroll
        for (int i = 0; i < 4; ++i)
            #pragma unroll
            for (int r = 0; r < 4; ++r) {
                const int row = i * 16 + quad * 4 + r;
                if (row < NTOK)
                    out[((size_t)b * NTOK + row) * 256 + gc] = P2[i][ct][r] + pb;
            }
    }
}

extern "C" void kernel_launch(void* const* d_in, const int* in_sizes, int n_in,
                              void* d_out, int out_size, void* d_ws, size_t ws_size,
                              hipStream_t stream) {
    const float* x      = (const float*)d_in[0];   // [4096,49,256]
    const float* mask   = (const float*)d_in[1];   // [4096,1,49,49]
    const float* qkv_w  = (const float*)d_in[2];   // [256,768]
    const float* qkv_b  = (const float*)d_in[3];   // [768]
    const float* rpb    = (const float*)d_in[4];   // [169,8]
    const float* proj_w = (const float*)d_in[5];   // [256,256]
    const float* proj_b = (const float*)d_in[6];   // [256]
    float* outp = (float*)d_out;

    u16* qkv      = (u16*)d_ws;                     // 200704*768 bf16
    u16* qkv_wT   = qkv + (size_t)200704 * 768;     // 768*256
    u16* proj_wT  = qkv_wT + 768 * 256;             // 256*256
    float* bias_p = (float*)(proj_wT + 256 * 256);  // 8*64*64 f32 (padded bias)

    prep_weights<<<1152, 256, 0, stream>>>(qkv_w, proj_w, rpb, qkv_wT, proj_wT, bias_p);
    qkv_gemm<<<1568 * 3, 512, 0, stream>>>(x, qkv_wT, qkv_b, qkv);
    attn_proj<<<4096, 512, 0, stream>>>(qkv, mask, bias_p, proj_wT, proj_b, outp);
}

// Round 2
// 824.908 us; speedup vs baseline: 1.0875x; 1.0875x over previous
//
#include <hip/hip_runtime.h>
#include <cstdint>
#include <cstddef>

// WindowAttention: B=4096 windows, N=49 tokens, DIM=256, NH=8, HD=32.
// K0 weights->bf16T + padded bias table, K1 qkv GEMM (NO xcd swizzle: K1's
// sequential write order leaves k/v segments L3-resident for K2 -- the
// swizzle destroyed that handoff, +260MB refetch), K2 fused attn+proj v3:
// reverse window order (consume freshest L3 lines first), swapped QK^T,
// in-register softmax, P via cvt_pk_bf16 + ds_bpermute quad exchange,
// mask staged in LDS, bias from padded table, OutS aliased onto Vt
// -> 47 KB LDS -> 3 blocks/CU.

#define NTOK 49
#define SCALE 0.17677669529663687f

typedef unsigned short u16;
typedef __attribute__((ext_vector_type(8))) short short8;
typedef __attribute__((ext_vector_type(4))) float f32x4;

__device__ __forceinline__ u16 f2bf(float f) {
    unsigned int u = __float_as_uint(f);
    u = (u + 0x7FFFu + ((u >> 16) & 1u)) >> 16;   // RNE
    return (u16)u;
}

__device__ __forceinline__ unsigned cvt_pk_bf16(float lo, float hi) {
    unsigned r;
    asm("v_cvt_pk_bf16_f32 %0, %1, %2" : "=v"(r) : "v"(lo), "v"(hi));
    return r;
}

__device__ __forceinline__ void async_lds16(void* lds, const void* g) {
    __builtin_amdgcn_global_load_lds(
        (const __attribute__((address_space(1))) void*)g,
        (__attribute__((address_space(3))) void*)lds, 16, 0, 0);
}

// ---------------- K0: weights -> bf16T + padded bias table -----------------
__global__ void prep_weights(const float* __restrict__ qkv_w,
                             const float* __restrict__ proj_w,
                             const float* __restrict__ rpb,
                             u16* __restrict__ qkv_wT,
                             u16* __restrict__ proj_wT,
                             float* __restrict__ bias_p) {
    int i = blockIdx.x * 256 + threadIdx.x;
    if (i < 768 * 256) {
        int oc = i >> 8, k = i & 255;
        qkv_wT[i] = f2bf(qkv_w[k * 768 + oc]);
    }
    int j = i - 768 * 256;
    if (j >= 0 && j < 256 * 256) {
        int oc = j >> 8, k = j & 255;
        proj_wT[j] = f2bf(proj_w[k * 256 + oc]);
    }
    int m = i - (768 * 256 + 256 * 256);
    if (m >= 0 && m < 8 * 64 * 64) {
        int h = m >> 12, q = (m >> 6) & 63, k = m & 63;
        float v = -1e30f;
        if (q < NTOK && k < NTOK) {
            int qr = q / 7, qc = q - qr * 7;
            int kr = k / 7, kc = k - kr * 7;
            v = rpb[((qr - kr + 6) * 13 + (qc - kc + 6)) * 8 + h];
        }
        bias_p[m] = v;
    }
}

// ---------------- K1: qkv = x @ qkv_w + b, q pre-scaled, bf16 out ----------
// M=200704 (1568 m-tiles of 128), N=768 (3 n-tiles of 256), K=256, BK=64.
// 512 thr = 8 waves (2m x 4n), 64x64 per wave. Sequential blockIdx on
// purpose: q/k/v segments are written in order, so L3 hands k+v (+q tail)
// to K2 for free.
__global__ __launch_bounds__(512, 4) void qkv_gemm(
        const float* __restrict__ x, const u16* __restrict__ wT,
        const float* __restrict__ bias, u16* __restrict__ qkv) {
    __shared__ __align__(16) u16 As[128 * 64];   // unpadded (m97 pattern)
    __shared__ __align__(16) u16 Bs[256 * 64];   // unpadded: global_load_lds dest
    const int bid = blockIdx.x;
    const int m0 = (bid % 1568) * 128, n0 = (bid / 1568) * 256;
    const int t = threadIdx.x;
    const int lane = t & 63, w = t >> 6;
    const int quad = lane >> 4, l16 = lane & 15;
    const int wm = w & 1, wn = w >> 1;
    const int ar = t >> 2, ac = (t & 3) * 16;          // A staging: 1 row-quarter
    const int br = t >> 3, bc = (t & 7) * 8;           // B staging row/col (elems)
    f32x4 acc[4][4] = {};
    for (int kk = 0; kk < 256; kk += 64) {
        #pragma unroll
        for (int c = 0; c < 4; ++c)                    // B: 256x64 bf16, async DMA
            async_lds16(&Bs[c * 4096 + t * 8],
                        wT + (size_t)(n0 + c * 64 + br) * 256 + kk + bc);
        {                                               // A: 128x64 f32 -> bf16
            const float* src = x + (size_t)(m0 + ar) * 256 + kk + ac;
            const f32x4 v0 = *(const f32x4*)(src);
            const f32x4 v1 = *(const f32x4*)(src + 4);
            const f32x4 v2 = *(const f32x4*)(src + 8);
            const f32x4 v3 = *(const f32x4*)(src + 12);
            ushort4 p0, p1, p2, p3;
            p0.x=f2bf(v0.x); p0.y=f2bf(v0.y); p0.z=f2bf(v0.z); p0.w=f2bf(v0.w);
            p1.x=f2bf(v1.x); p1.y=f2bf(v1.y); p1.z=f2bf(v1.z); p1.w=f2bf(v1.w);
            p2.x=f2bf(v2.x); p2.y=f2bf(v2.y); p2.z=f2bf(v2.z); p2.w=f2bf(v2.w);
            p3.x=f2bf(v3.x); p3.y=f2bf(v3.y); p3.z=f2bf(v3.z); p3.w=f2bf(v3.w);
            uint4 q0, q1;
            q0.x=*(unsigned*)&p0.x; q0.y=*(unsigned*)&p0.z;
            q0.z=*(unsigned*)&p1.x; q0.w=*(unsigned*)&p1.z;
            q1.x=*(unsigned*)&p2.x; q1.y=*(unsigned*)&p2.z;
            q1.z=*(unsigned*)&p3.x; q1.w=*(unsigned*)&p3.z;
            *(uint4*)&As[ar * 64 + ac] = q0;
            *(uint4*)&As[ar * 64 + ac + 8] = q1;
        }
        __syncthreads();
        #pragma unroll
        for (int ks = 0; ks < 2; ++ks) {
            short8 af[4], bfr[4];
            #pragma unroll
            for (int i = 0; i < 4; ++i)
                af[i] = *(const short8*)&As[(wm * 64 + i * 16 + l16) * 64 + ks * 32 + quad * 8];
            #pragma unroll
            for (int j = 0; j < 4; ++j)
                bfr[j] = *(const short8*)&Bs[(wn * 64 + j * 16 + l16) * 64 + ks * 32 + quad * 8];
            #pragma unroll
            for (int i = 0; i < 4; ++i)
                #pragma unroll
                for (int j = 0; j < 4; ++j)
                    acc[i][j] = __builtin_amdgcn_mfma_f32_16x16x32_bf16(
                        af[i], bfr[j], acc[i][j], 0, 0, 0);
        }
        __syncthreads();
    }
    #pragma unroll
    for (int j = 0; j < 4; ++j) {
        const int gc = n0 + wn * 64 + j * 16 + l16;
        const float bv = bias[gc];
        const float scl = (gc < 256) ? SCALE : 1.0f;
        #pragma unroll
        for (int i = 0; i < 4; ++i) {
            const int gr = m0 + wm * 64 + i * 16 + quad * 4;
            #pragma unroll
            for (int r = 0; r < 4; ++r)
                qkv[(size_t)(gr + r) * 768 + gc] = f2bf((acc[i][j][r] + bv) * scl);
        }
    }
}

// ---------------- K2: per-window attention + projection (v3) ---------------
// 1 block / window, 512 thr = 8 waves = 1 head each.
// LDS: SMEM 34816 B (Vt, later aliased by OutS) + maskL 13328 B = 47 KB
// -> 3 blocks/CU. Windows processed in REVERSE so the qkv rows K1 wrote
// last (still L3-resident) are consumed first.
__global__ __launch_bounds__(512, 6) void attn_proj(
        const u16* __restrict__ qkv, const float* __restrict__ mask,
        const float* __restrict__ bias_p, const u16* __restrict__ projT,
        const float* __restrict__ proj_b, float* __restrict__ out) {
    __shared__ __align__(16) u16 SMEM[8 * 32 * 68];   // V^T [h][d][tok]; OutS overlay later
    __shared__ __align__(16) float maskL[49 * 68];    // mask staged once per block
    const int b = 4095 - blockIdx.x;                  // reverse: freshest L3 first
    const int t = threadIdx.x;
    const int lane = t & 63, h = t >> 6;              // wave == head
    const int quad = lane >> 4, l16 = lane & 15;
    const short8 zf = {0, 0, 0, 0, 0, 0, 0, 0};
    const f32x4 zero4 = {0.f, 0.f, 0.f, 0.f};
    const u16* qrow = qkv + (size_t)b * NTOK * 768;
    const float* mrow = mask + (size_t)b * (NTOK * NTOK);

    // ---- stage V^T: wave h stages head h; paired tokens -> b32 writes ----
    {
        unsigned* vw = (unsigned*)&SMEM[h * 2176];
        const int tp = lane & 31;                     // token pair index
        const int dh = (lane >> 5) * 4;               // d sub-quad
        const int n0 = 2 * tp;
        #pragma unroll
        for (int it = 0; it < 4; ++it) {
            const int d0 = it * 8 + dh;
            ushort4 g0 = {0, 0, 0, 0}, g1 = {0, 0, 0, 0};
            if (n0 < NTOK)     g0 = *(const ushort4*)(qrow + n0 * 768 + 512 + h * 32 + d0);
            if (n0 + 1 < NTOK) g1 = *(const ushort4*)(qrow + (n0 + 1) * 768 + 512 + h * 32 + d0);
            vw[(d0 + 0) * 34 + tp] = (unsigned)g0.x | ((unsigned)g1.x << 16);
            vw[(d0 + 1) * 34 + tp] = (unsigned)g0.y | ((unsigned)g1.y << 16);
            vw[(d0 + 2) * 34 + tp] = (unsigned)g0.z | ((unsigned)g1.z << 16);
            vw[(d0 + 3) * 34 + tp] = (unsigned)g0.w | ((unsigned)g1.w << 16);
        }
    }
    // ---- stage mask [49][68] f32, once per block (waves share) ----
    for (int r = h; r < NTOK; r += 8) {
        maskL[r * 68 + lane] = (lane < NTOK) ? mrow[r * 49 + lane] : 0.f;
        if (lane < 4) maskL[r * 68 + 64 + lane] = 0.f;
    }
    __syncthreads();

    // ---- V frags (B operand for PV) into registers ----
    short8 bV[2][2];
    {
        const u16* vt = &SMEM[h * 2176];
        #pragma unroll
        for (int ct = 0; ct < 2; ++ct)
            #pragma unroll
            for (int ks = 0; ks < 2; ++ks)
                bV[ct][ks] = *(const short8*)&vt[(ct * 16 + l16) * 68 + ks * 32 + quad * 8];
    }
    // K frags (A operand of swapped QK^T): K token rows, contiguous d
    short8 aK[4];
    #pragma unroll
    for (int ki = 0; ki < 4; ++ki) {
        const int kt = ki * 16 + l16;
        aK[ki] = (kt < NTOK) ? *(const short8*)(qrow + kt * 768 + 256 + h * 32 + quad * 8) : zf;
    }
    // Q frags (B operand), all 4 q-tiles preloaded -> latency hidden
    short8 bQ[4];
    #pragma unroll
    for (int qj = 0; qj < 4; ++qj) {
        const int qtok = qj * 16 + l16;
        bQ[qj] = (qtok < NTOK)
            ? *(const short8*)(qrow + qtok * 768 + h * 32 + quad * 8) : zf;
    }
    __syncthreads();   // all bV register-resident before OutS overlays Vt

    u16* OutS = SMEM;  // overlay: [49][264] bf16, 25.9 KB <= 34.8 KB
    const float* bias_h = bias_p + (h << 12);
    const int saA = (((quad & 1) << 5) + l16) << 2;  // bpermute byte addr (quads 0/2)
    const int saB = saA + 64;                        // +16 lanes (quads 1/3)
    const bool hiK = (quad >> 1) != 0;

    // ---- per q-tile: QK^T (swapped) -> softmax in regs -> PV -> OutS ----
    #pragma unroll
    for (int qj = 0; qj < 4; ++qj) {
        const int qtok = qj * 16 + l16;              // this lane's q column
        f32x4 S[4];                                   // S^T[k=16ki+4*quad+r][qtok]
        #pragma unroll
        for (int ki = 0; ki < 4; ++ki)
            S[ki] = __builtin_amdgcn_mfma_f32_16x16x32_bf16(aK[ki], bQ[qj], zero4, 0, 0, 0);
        // bias (padded table: -1e30 outside 49x49) + mask, float4 loads
        const int qc = (qtok < NTOK) ? qtok : 0;
        #pragma unroll
        for (int ki = 0; ki < 4; ++ki) {
            const f32x4 bb = *(const f32x4*)(bias_h + qtok * 64 + ki * 16 + quad * 4);
            const f32x4 mm = *(const f32x4*)(&maskL[qc * 68 + ki * 16 + quad * 4]);
            S[ki] += bb + mm;
        }
        // softmax over k: 16 in-lane + cross-quad (lanes l16 ^ 16 ^ 32)
        float mx = fmaxf(fmaxf(fmaxf(S[0][0], S[0][1]), fmaxf(S[0][2], S[0][3])),
                         fmaxf(fmaxf(S[1][0], S[1][1]), fmaxf(S[1][2], S[1][3])));
        mx = fmaxf(mx, fmaxf(fmaxf(fmaxf(S[2][0], S[2][1]), fmaxf(S[2][2], S[2][3])),
                             fmaxf(fmaxf(S[3][0], S[3][1]), fmaxf(S[3][2], S[3][3]))));
        mx = fmaxf(mx, __shfl_xor(mx, 16));
        mx = fmaxf(mx, __shfl_xor(mx, 32));
        float sum = 0.f;
        #pragma unroll
        for (int ki = 0; ki < 4; ++ki)
            #pragma unroll
            for (int r = 0; r < 4; ++r) {
                const float e = __expf(S[ki][r] - mx);
                S[ki][r] = e;
                sum += e;
            }
        sum += __shfl_xor(sum, 16);
        sum += __shfl_xor(sum, 32);
        const float rinv = 1.0f / sum;
        // pack P^T to bf16 pairs (r01, r23 per ki)
        unsigned pk2[4][2];
        #pragma unroll
        for (int ki = 0; ki < 4; ++ki) {
            pk2[ki][0] = cvt_pk_bf16(S[ki][0] * rinv, S[ki][1] * rinv);
            pk2[ki][1] = cvt_pk_bf16(S[ki][2] * rinv, S[ki][3] * rinv);
        }
        // quad exchange: A-frag word f of k-tile ks comes from lane
        // (2*(quad&1)+(f>>1))*16+l16, register pk2[2ks+(quad>>1)][f&1]
        f32x4 O0 = zero4, O1 = zero4;
        #pragma unroll
        for (int ks = 0; ks < 2; ++ks) {
            const int j0 = 2 * ks, j1 = 2 * ks + 1;
            const unsigned a0 = __builtin_amdgcn_ds_bpermute(saA, (int)pk2[j0][0]);
            const unsigned b0 = __builtin_amdgcn_ds_bpermute(saA, (int)pk2[j1][0]);
            const unsigned a1 = __builtin_amdgcn_ds_bpermute(saA, (int)pk2[j0][1]);
            const unsigned b1 = __builtin_amdgcn_ds_bpermute(saA, (int)pk2[j1][1]);
            const unsigned a2 = __builtin_amdgcn_ds_bpermute(saB, (int)pk2[j0][0]);
            const unsigned b2 = __builtin_amdgcn_ds_bpermute(saB, (int)pk2[j1][0]);
            const unsigned a3 = __builtin_amdgcn_ds_bpermute(saB, (int)pk2[j0][1]);
            const unsigned b3 = __builtin_amdgcn_ds_bpermute(saB, (int)pk2[j1][1]);
            union { unsigned u[4]; short8 s; } ap;
            ap.u[0] = hiK ? b0 : a0;
            ap.u[1] = hiK ? b1 : a1;
            ap.u[2] = hiK ? b2 : a2;
            ap.u[3] = hiK ? b3 : a3;
            O0 = __builtin_amdgcn_mfma_f32_16x16x32_bf16(ap.s, bV[0][ks], O0, 0, 0, 0);
            O1 = __builtin_amdgcn_mfma_f32_16x16x32_bf16(ap.s, bV[1][ks], O1, 0, 0, 0);
        }
        #pragma unroll
        for (int r = 0; r < 4; ++r) {
            const int row = qj * 16 + quad * 4 + r;
            if (row < NTOK) {
                OutS[row * 264 + h * 32 + l16]      = f2bf(O0[r]);
                OutS[row * 264 + h * 32 + 16 + l16] = f2bf(O1[r]);
            }
        }
    }
    __syncthreads();

    // ---- proj: [49x256] @ [256x256], wave h -> out cols h*32..h*32+31 ----
    f32x4 P2[4][2] = {};
    #pragma unroll
    for (int ks = 0; ks < 8; ++ks) {
        short8 bW[2];
        #pragma unroll
        for (int ct = 0; ct < 2; ++ct)
            bW[ct] = *(const short8*)(projT + (size_t)(h * 32 + ct * 16 + l16) * 256
                                      + ks * 32 + quad * 8);
        #pragma unroll
        for (int i = 0; i < 4; ++i) {
            const int row = i * 16 + l16;
            const short8 aO = (row < NTOK) ? *(const short8*)&OutS[row * 264 + ks * 32 + quad * 8] : zf;
            #pragma unroll
            for (int ct = 0; ct < 2; ++ct)
                P2[i][ct] = __builtin_amdgcn_mfma_f32_16x16x32_bf16(aO, bW[ct], P2[i][ct], 0, 0, 0);
        }
    }
    #pragma unroll
    for (int ct = 0; ct < 2; ++ct) {
        const int gc = h * 32 + ct * 16 + l16;
        const float pb = proj_b[gc];
        #pragma unroll
        for (int i = 0; i < 4; ++i)
            #pragma unroll
            for (int r = 0; r < 4; ++r) {
                const int row = i * 16 + quad * 4 + r;
                if (row < NTOK)
                    out[((size_t)b * NTOK + row) * 256 + gc] = P2[i][ct][r] + pb;
            }
    }
}

extern "C" void kernel_launch(void* const* d_in, const int* in_sizes, int n_in,
                              void* d_out, int out_size, void* d_ws, size_t ws_size,
                              hipStream_t stream) {
    const float* x      = (const float*)d_in[0];   // [4096,49,256]
    const float* mask   = (const float*)d_in[1];   // [4096,1,49,49]
    const float* qkv_w  = (const float*)d_in[2];   // [256,768]
    const float* qkv_b  = (const float*)d_in[3];   // [768]
    const float* rpb    = (const float*)d_in[4];   // [169,8]
    const float* proj_w = (const float*)d_in[5];   // [256,256]
    const float* proj_b = (const float*)d_in[6];   // [256]
    float* outp = (float*)d_out;

    u16* qkv      = (u16*)d_ws;                     // 200704*768 bf16
    u16* qkv_wT   = qkv + (size_t)200704 * 768;     // 768*256
    u16* proj_wT  = qkv_wT + 768 * 256;             // 256*256
    float* bias_p = (float*)(proj_wT + 256 * 256);  // 8*64*64 f32 (padded bias)

    prep_weights<<<1152, 256, 0, stream>>>(qkv_w, proj_w, rpb, qkv_wT, proj_wT, bias_p);
    qkv_gemm<<<1568 * 3, 512, 0, stream>>>(x, qkv_wT, qkv_b, qkv);
    attn_proj<<<4096, 512, 0, stream>>>(qkv, mask, bias_p, proj_wT, proj_b, outp);
}